// Round 3
// baseline (228.339 us; speedup 1.0000x reference)
//
#include <hip/hip_runtime.h>

#define N_NODES 2048
#define BN_TOTAL 16384   // B*N = 8*2048

typedef float vf4 __attribute__((ext_vector_type(4)));

// Kernel 1: fused conv1x3 (x3) + sigmoid/relu + projection to si/sj.
// One WAVE per node: lane = time-step to (0..61 active), each lane computes
// all 4 output channels. Weights/biases are block-uniform -> s_load (SGPRs).
// No cross-wave reduction; lane 0 stores si/sj directly. 4 nodes/block.
__global__ __launch_bounds__(256) void k_sisj(
    const float* __restrict__ X,
    const float* __restrict__ cw1, const float* __restrict__ cb1,
    const float* __restrict__ cw2, const float* __restrict__ cb2,
    const float* __restrict__ cw3, const float* __restrict__ cb3,
    const float* __restrict__ fcw,
    float* __restrict__ si, float* __restrict__ sj)
{
    __shared__ float Xs[4096];          // 4 nodes x 64 x 16
    const int tid  = threadIdx.x;
    const int wid  = tid >> 6;
    const int lane = tid & 63;
    const int bn0  = blockIdx.x * 4;

    // Stage 4 consecutive node tiles (16 KB contiguous), coalesced float4.
    #pragma unroll
    for (int q = 0; q < 4; ++q) {
        const int idx = q * 256 + tid;
        *(vf4*)&Xs[idx * 4] = *(const vf4*)(X + (size_t)bn0 * 1024 + (size_t)idx * 4);
    }
    __syncthreads();

    const int to = lane;
    const float* __restrict__ xb = &Xs[wid * 1024];

    float pi = 0.f, pj = 0.f;
    if (to < 62) {
        // 3 X rows (48 floats) via 12 ds_read_b128.
        vf4 xr[12];
        #pragma unroll
        for (int dt = 0; dt < 3; ++dt)
            #pragma unroll
            for (int q = 0; q < 4; ++q)
                xr[dt * 4 + q] = *(const vf4*)&xb[(to + dt) * 16 + q * 4];
        const float* xf = (const float*)xr;    // [dt*16 + ci]

        // Block-uniform biases -> s_load_dwordx4.
        const vf4 b1 = *(const vf4*)cb1;
        const vf4 b2 = *(const vf4*)cb2;
        const vf4 b3 = *(const vf4*)cb3;

        float acc[12];
        #pragma unroll
        for (int c = 0; c < 4; ++c) { acc[c] = b1[c]; acc[4 + c] = b2[c]; acc[8 + c] = b3[c]; }

        const float* __restrict__ cw[3] = {cw1, cw2, cw3};
        #pragma unroll
        for (int k = 0; k < 3; ++k)
            #pragma unroll
            for (int c = 0; c < 4; ++c) {
                const float* __restrict__ w = cw[k] + c * 48;   // uniform -> s_load
                float a = acc[k * 4 + c];
                #pragma unroll
                for (int ci = 0; ci < 16; ++ci)
                    #pragma unroll
                    for (int dt = 0; dt < 3; ++dt)
                        a = fmaf(xf[dt * 16 + ci], w[ci * 3 + dt], a);
                acc[k * 4 + c] = a;
            }

        // temp = y1 + sigmoid(y2); t = relu(temp + y3); project onto wi/wj.
        const vf4 wiv = *(const vf4*)(fcw + to * 4);          // aligned float4
        const vf4 wjv = *(const vf4*)(fcw + 248 + to * 4);    // 248%4==0 -> aligned
        #pragma unroll
        for (int c = 0; c < 4; ++c) {
            const float sig = 1.f / (1.f + __expf(-acc[4 + c]));
            const float tv  = acc[c] + sig + acc[8 + c];
            const float t   = tv > 0.f ? tv : 0.f;
            pi = fmaf(t, wiv[c], pi);
            pj = fmaf(t, wjv[c], pj);
        }
    }

    #pragma unroll
    for (int off = 32; off > 0; off >>= 1) {
        pi += __shfl_xor(pi, off);
        pj += __shfl_xor(pj, off);
    }
    if (lane == 0) {
        si[bn0 + wid] = pi;
        sj[bn0 + wid] = pj;
    }
}

// Kernel 2: one block per i, all 8 batches per block. A row i is loaded ONCE
// (NT) and reused for all b; sj rows for all 8 b preloaded to registers.
// Phase A: 8 partial sums -> LDS; ONE barrier; Phase B: recompute exp,
// scale, NT-store 8 output rows. Masked entries contribute exp(0) to the
// denominator exactly as the reference (mask-before-softmax, no max-sub:
// scores are O(1), exp(s)/sum(exp(s)) is mathematically identical).
__global__ __launch_bounds__(256) void k_att(
    const float* __restrict__ A,
    const float* __restrict__ si, const float* __restrict__ sj,
    const float* __restrict__ fcb,
    float* __restrict__ out)
{
    __shared__ float red[8][4];

    const int i    = blockIdx.x;          // 0..2047
    const int tid  = threadIdx.x;
    const int wid  = tid >> 6;
    const int lane = tid & 63;

    // A row i (single physical read of A across the whole kernel).
    const vf4* __restrict__ Ar = (const vf4*)(A + (size_t)i * N_NODES);
    vf4 a4[2];
    a4[0] = __builtin_nontemporal_load(Ar + tid);
    a4[1] = __builtin_nontemporal_load(Ar + tid + 256);

    // All 8 sj rows (L2-resident, 64 KB total in the device).
    vf4 sjv[8][2];
    #pragma unroll
    for (int b = 0; b < 8; ++b) {
        const vf4* __restrict__ sb = (const vf4*)(sj + b * N_NODES);
        sjv[b][0] = sb[tid];
        sjv[b][1] = sb[tid + 256];
    }
    const float fcb0 = fcb[0];
    float cb[8];
    #pragma unroll
    for (int b = 0; b < 8; ++b) cb[b] = si[b * N_NODES + i] + fcb0;  // uniform -> s_load

    // Phase A: per-b partial sums.
    #pragma unroll
    for (int b = 0; b < 8; ++b) {
        float s = 0.f;
        #pragma unroll
        for (int u = 0; u < 2; ++u)
            #pragma unroll
            for (int q = 0; q < 4; ++q) {
                float sc = cb[b] + sjv[b][u][q];
                sc = (sc >= 0.f) ? sc : 0.01f * sc;        // leaky_relu
                const float at = (a4[u][q] != 0.f) ? sc : 0.f;
                s += __expf(at);
            }
        #pragma unroll
        for (int off = 32; off > 0; off >>= 1) s += __shfl_xor(s, off);
        if (lane == 0) red[b][wid] = s;
    }
    __syncthreads();

    // Phase B: finalize sums, recompute exp, scale by A, NT-store.
    #pragma unroll
    for (int b = 0; b < 8; ++b) {
        const float inv = 1.f / (red[b][0] + red[b][1] + red[b][2] + red[b][3]);
        vf4* __restrict__ orow = (vf4*)(out + ((size_t)b * N_NODES + i) * N_NODES);
        #pragma unroll
        for (int u = 0; u < 2; ++u) {
            vf4 o;
            #pragma unroll
            for (int q = 0; q < 4; ++q) {
                float sc = cb[b] + sjv[b][u][q];
                sc = (sc >= 0.f) ? sc : 0.01f * sc;
                const float at = (a4[u][q] != 0.f) ? sc : 0.f;
                o[q] = a4[u][q] * (__expf(at) * inv);
            }
            __builtin_nontemporal_store(o, orow + tid + u * 256);
        }
    }
}

extern "C" void kernel_launch(void* const* d_in, const int* in_sizes, int n_in,
                              void* d_out, int out_size, void* d_ws, size_t ws_size,
                              hipStream_t stream)
{
    const float* X   = (const float*)d_in[0];
    const float* A   = (const float*)d_in[1];
    const float* cw1 = (const float*)d_in[2];
    const float* cb1 = (const float*)d_in[3];
    const float* cw2 = (const float*)d_in[4];
    const float* cb2 = (const float*)d_in[5];
    const float* cw3 = (const float*)d_in[6];
    const float* cb3 = (const float*)d_in[7];
    const float* fcw = (const float*)d_in[8];
    const float* fcb = (const float*)d_in[9];
    float* out = (float*)d_out;

    float* si = (float*)d_ws;          // 16384 floats
    float* sj = si + BN_TOTAL;         // 16384 floats

    hipLaunchKernelGGL(k_sisj, dim3(BN_TOTAL / 4), dim3(256), 0, stream,
                       X, cw1, cb1, cw2, cb2, cw3, cb3, fcw, si, sj);
    hipLaunchKernelGGL(k_att, dim3(N_NODES), dim3(256), 0, stream,
                       A, si, sj, fcb, out);
}